// Round 1
// baseline (186.028 us; speedup 1.0000x reference)
//
#include <hip/hip_runtime.h>

#define NROWS 4096
#define NCOLS 32000
#define NV4   (NCOLS / 4)   // 8000 float4 per row
#define BLOCK 1024
#define EPSF  1e-10f

__device__ __forceinline__ float wave_reduce_sum(float v) {
#pragma unroll
  for (int o = 32; o > 0; o >>= 1) v += __shfl_down(v, o, 64);
  return v;
}

__global__ void zero_kernel(float* out) { out[0] = 0.0f; }

__global__ __launch_bounds__(BLOCK, 1)
void weak_loss_kernel(const float* __restrict__ scores,
                      const int* __restrict__ labels,
                      float* __restrict__ out) {
  extern __shared__ float lds[];   // NCOLS floats = 128000 B dynamic LDS
  __shared__ float wsum[16];
  __shared__ float bcast;

  const int row  = blockIdx.x;
  const int t    = threadIdx.x;
  const int lane = t & 63;
  const int wid  = t >> 6;

  const float4* __restrict__ rp4 = (const float4*)(scores + (size_t)row * NCOLS);
  float4* lds4 = (float4*)lds;

  // ---- Phase 1: stream row from HBM, exp(), stage in LDS, partial row-sum ----
  float partial = 0.0f;
  for (int j = t; j < NV4; j += BLOCK) {
    float4 v = rp4[j];
    float4 e;
    e.x = __expf(v.x);
    e.y = __expf(v.y);
    e.z = __expf(v.z);
    e.w = __expf(v.w);
    lds4[j] = e;
    partial += (e.x + e.y) + (e.z + e.w);
  }

  // ---- Block reduction for denominator d ----
  float ws = wave_reduce_sum(partial);
  if (lane == 0) wsum[wid] = ws;
  __syncthreads();
  if (wid == 0) {
    float v = (lane < 16) ? wsum[lane] : 0.0f;
    v = wave_reduce_sum(v);
    if (lane == 0) bcast = v + EPSF;
  }
  __syncthreads();

  const float d     = bcast;
  const float inv_d = 1.0f / d;
  const int   lab   = labels[row];
  const float p_lab = lds[lab] * inv_d;

  // ---- Phase 2: masked sum of -log1p(eps - p) ≈ p + p^2/2 + p^3/3 + p^4/4 ----
  float acc = 0.0f;
  for (int j = t; j < NV4; j += BLOCK) {
    float4 e = lds4[j];
    float pv[4] = {e.x, e.y, e.z, e.w};
#pragma unroll
    for (int k = 0; k < 4; ++k) {
      float p = pv[k] * inv_d;
      if (p < p_lab) {
        float c = fmaf(0.25f, p, 1.0f / 3.0f);  // 1/3 + p/4
        c = fmaf(c, p, 0.5f);                   // 1/2 + p/3 + p^2/4
        c = c * p;                              // p/2 + p^2/3 + p^3/4
        acc += fmaf(c, p, p);                   // p + p^2/2 + p^3/3 + p^4/4
      }
    }
  }

  // ---- Block reduction + global accumulate (loss = +mean of masked sums) ----
  float as = wave_reduce_sum(acc);
  if (lane == 0) wsum[wid] = as;
  __syncthreads();
  if (wid == 0) {
    float v = (lane < 16) ? wsum[lane] : 0.0f;
    v = wave_reduce_sum(v);
    if (lane == 0) atomicAdd(out, v * (1.0f / (float)NROWS));
  }
}

extern "C" void kernel_launch(void* const* d_in, const int* in_sizes, int n_in,
                              void* d_out, int out_size, void* d_ws, size_t ws_size,
                              hipStream_t stream) {
  const float* scores = (const float*)d_in[0];
  const int*   labels = (const int*)d_in[1];
  float*       out    = (float*)d_out;

  // 128000 B dynamic LDS exceeds the default 64 KB cap — raise it every call
  // (no static guards; the call is cheap and idempotent).
  hipFuncSetAttribute((const void*)weak_loss_kernel,
                      hipFuncAttributeMaxDynamicSharedMemorySize, NCOLS * 4);

  zero_kernel<<<1, 1, 0, stream>>>(out);
  weak_loss_kernel<<<NROWS, BLOCK, NCOLS * 4, stream>>>(scores, labels, out);
}

// Round 2
// 107.351 us; speedup vs baseline: 1.7329x; 1.7329x over previous
//
#include <hip/hip_runtime.h>

#define NROWS 4096
#define NCOLS 32000
#define NV8   (NCOLS / 8)   // 4000 half8 per row
#define BLOCK 1024
#define EPSF  1e-10f

typedef _Float16 half8 __attribute__((ext_vector_type(8)));

__device__ __forceinline__ float wave_reduce_sum(float v) {
#pragma unroll
  for (int o = 32; o > 0; o >>= 1) v += __shfl_down(v, o, 64);
  return v;
}

__global__ void zero_kernel(float* out) { out[0] = 0.0f; }

__global__ __launch_bounds__(BLOCK, 8)
void weak_loss_kernel(const float* __restrict__ scores,
                      const int* __restrict__ labels,
                      float* __restrict__ out) {
  extern __shared__ _Float16 lds[];   // NCOLS halves = 64000 B dynamic LDS
  __shared__ float wsum[16];
  __shared__ float bcast;

  const int row  = blockIdx.x;
  const int t    = threadIdx.x;
  const int lane = t & 63;
  const int wid  = t >> 6;

  const float4* __restrict__ rp4 = (const float4*)(scores + (size_t)row * NCOLS);
  half8* lds8 = (half8*)lds;

  // ---- Phase 1: stream row from HBM, exp() in f32, stage fp16 in LDS,
  //      accumulate the denominator in f32 (full precision) ----
  float partial = 0.0f;
  for (int j = t; j < NV8; j += BLOCK) {
    float4 a = rp4[2 * j];
    float4 b = rp4[2 * j + 1];
    float e0 = __expf(a.x), e1 = __expf(a.y), e2 = __expf(a.z), e3 = __expf(a.w);
    float e4 = __expf(b.x), e5 = __expf(b.y), e6 = __expf(b.z), e7 = __expf(b.w);
    half8 h;
    h[0] = (_Float16)e0; h[1] = (_Float16)e1; h[2] = (_Float16)e2; h[3] = (_Float16)e3;
    h[4] = (_Float16)e4; h[5] = (_Float16)e5; h[6] = (_Float16)e6; h[7] = (_Float16)e7;
    lds8[j] = h;
    partial += ((e0 + e1) + (e2 + e3)) + ((e4 + e5) + (e6 + e7));
  }

  // ---- Block reduction for denominator d ----
  float ws = wave_reduce_sum(partial);
  if (lane == 0) wsum[wid] = ws;
  __syncthreads();
  if (wid == 0) {
    float v = (lane < 16) ? wsum[lane] : 0.0f;
    v = wave_reduce_sum(v);
    if (lane == 0) bcast = v + EPSF;
  }
  __syncthreads();

  const float     inv_d  = 1.0f / bcast;
  const _Float16  eh_lab = lds[labels[row]];

  // ---- Phase 2: masked sum of -log1p(eps - p) ≈ p + p^2/2 + p^3/3 + p^4/4.
  //      Mask compare in the half domain (monotone under *inv_d, both sides
  //      rounded identically → matches reference up to near-ULP ties). ----
  float acc = 0.0f;
  for (int j = t; j < NV8; j += BLOCK) {
    half8 h = lds8[j];
#pragma unroll
    for (int k = 0; k < 8; ++k) {
      if (h[k] < eh_lab) {
        float p = (float)h[k] * inv_d;
        float c = fmaf(0.25f, p, 1.0f / 3.0f);  // 1/3 + p/4
        c = fmaf(c, p, 0.5f);                   // 1/2 + p/3 + p^2/4
        c = c * p;                              // p/2 + p^2/3 + p^3/4
        acc += fmaf(c, p, p);                   // p + p^2/2 + p^3/3 + p^4/4
      }
    }
  }

  // ---- Block reduction + global accumulate (loss = +mean of masked sums) ----
  float as = wave_reduce_sum(acc);
  if (lane == 0) wsum[wid] = as;
  __syncthreads();
  if (wid == 0) {
    float v = (lane < 16) ? wsum[lane] : 0.0f;
    v = wave_reduce_sum(v);
    if (lane == 0) atomicAdd(out, v * (1.0f / (float)NROWS));
  }
}

extern "C" void kernel_launch(void* const* d_in, const int* in_sizes, int n_in,
                              void* d_out, int out_size, void* d_ws, size_t ws_size,
                              hipStream_t stream) {
  const float* scores = (const float*)d_in[0];
  const int*   labels = (const int*)d_in[1];
  float*       out    = (float*)d_out;

  hipFuncSetAttribute((const void*)weak_loss_kernel,
                      hipFuncAttributeMaxDynamicSharedMemorySize, NCOLS * 2);

  zero_kernel<<<1, 1, 0, stream>>>(out);
  weak_loss_kernel<<<NROWS, BLOCK, NCOLS * 2, stream>>>(scores, labels, out);
}